// Round 1
// baseline (3860.641 us; speedup 1.0000x reference)
//
#include <hip/hip_runtime.h>

// ---------------------------------------------------------------------------
// 3-layer GraphSAGE (DGL GraphConv norm='left') on N=100k nodes, E=1M edges,
// D=H=O=64, fp32 throughout.
//   layer1: agg[dst] += (x  * r_out)[src];  h1 = relu([x ,agg]@W1 + b1)
//   layer2: agg[src] += (h1 * r_in )[dst];  h2 = relu([h1,agg]@W2 + b2)
//   layer3: agg both dirs with r_und;       out =     [h2,agg]@W3 + b3
// r_out = 1/max(outdeg,1), r_in = 1/max(indeg,1), r_und = 1/max(outdeg+indeg,1)
// ---------------------------------------------------------------------------

__global__ void deg_count_k(const int* __restrict__ src, const int* __restrict__ dst,
                            int* __restrict__ c_out, int* __restrict__ c_in, int E) {
    int t = blockIdx.x * blockDim.x + threadIdx.x;
    if (t < E) {
        atomicAdd(&c_out[src[t]], 1);
        atomicAdd(&c_in[dst[t]], 1);
    }
}

__global__ void deg_finalize_k(const int* __restrict__ c_out, const int* __restrict__ c_in,
                               float* __restrict__ r_out, float* __restrict__ r_in,
                               float* __restrict__ r_und, int N) {
    int t = blockIdx.x * blockDim.x + threadIdx.x;
    if (t < N) {
        int a = c_out[t], b = c_in[t];
        int au = a < 1 ? 1 : a;
        int bu = b < 1 ? 1 : b;
        int cu = (a + b) < 1 ? 1 : (a + b);
        r_out[t] = 1.0f / (float)au;
        r_in[t]  = 1.0f / (float)bu;
        r_und[t] = 1.0f / (float)cu;
    }
}

// y[row] = in[row] * r[row], vectorized float4 (16 float4 per 64-wide row)
__global__ void scale_rows_k(const float* __restrict__ in, const float* __restrict__ r,
                             float* __restrict__ out, int n4) {
    int t = blockIdx.x * blockDim.x + threadIdx.x;
    if (t < n4) {
        float s = r[t >> 4];
        float4 v = ((const float4*)in)[t];
        v.x *= s; v.y *= s; v.z *= s; v.w *= s;
        ((float4*)out)[t] = v;
    }
}

// agg[d[e]] += y[s[e]] ; one thread per (edge, feature)
__global__ void scatter_add_k(const float* __restrict__ y, const int* __restrict__ s,
                              const int* __restrict__ d, float* __restrict__ agg, int E) {
    int t = blockIdx.x * blockDim.x + threadIdx.x;
    int e = t >> 6, f = t & 63;
    if (e < E) {
        int sn = s[e], dn = d[e];
        atomicAdd(&agg[(size_t)dn * 64 + f], y[(size_t)sn * 64 + f]);
    }
}

// out = [X, A] @ W + B  (optionally relu). W: [128][64] row-major.
// Block: 256 threads -> 64 rows x 64 cols tile, per-thread 4x4 register tile.
// LDS: W (32KB) + X tile (16KB) + A tile (16KB) = 64KB exactly.
// X/A tiles use an XOR swizzle (col ^ ((row&12)<<1)) so the 4 per-instruction
// row reads (rows r0 in {0,4,8,12} across lanes, stride-64 dwords) land in 4
// distinct banks instead of one.
template <bool RELU>
__global__ __launch_bounds__(256, 2) void gemm_cat_k(
    const float* __restrict__ X, const float* __restrict__ A,
    const float* __restrict__ W, const float* __restrict__ B,
    float* __restrict__ out, int N) {
    __shared__ float sW[128 * 64];
    __shared__ float sX[64 * 64];
    __shared__ float sA[64 * 64];
    const int tid = threadIdx.x;

    for (int i = tid; i < 128 * 64; i += 256) sW[i] = W[i];

    const int row0 = blockIdx.x * 64;
    for (int i = tid; i < 64 * 64; i += 256) {
        int r = i >> 6, c = i & 63;
        int gr = row0 + r;
        int sc = c ^ ((r & 12) << 1);
        float xv = 0.f, av = 0.f;
        if (gr < N) {
            xv = X[(size_t)gr * 64 + c];
            av = A[(size_t)gr * 64 + c];
        }
        sX[(r << 6) + sc] = xv;
        sA[(r << 6) + sc] = av;
    }
    __syncthreads();

    const int c0 = (tid & 15) << 2;   // output col base
    const int r0 = (tid >> 4) << 2;   // output row base (within tile)
    const int sw = (r0 & 12) << 1;    // swizzle for this thread's rows

    float4 bv = *(const float4*)(B + c0);
    float acc[4][4];
#pragma unroll
    for (int i = 0; i < 4; ++i) {
        acc[i][0] = bv.x; acc[i][1] = bv.y; acc[i][2] = bv.z; acc[i][3] = bv.w;
    }

#pragma unroll
    for (int k = 0; k < 128; ++k) {
        const float* sT = (k < 64) ? sX : sA;   // resolves at compile time (unrolled)
        const int kk = k & 63;
        const int kx = kk ^ sw;
        float4 w = *(const float4*)&sW[(k << 6) + c0];
        float a0 = sT[((r0 + 0) << 6) + kx];
        float a1 = sT[((r0 + 1) << 6) + kx];
        float a2 = sT[((r0 + 2) << 6) + kx];
        float a3 = sT[((r0 + 3) << 6) + kx];
        acc[0][0] = fmaf(a0, w.x, acc[0][0]);
        acc[0][1] = fmaf(a0, w.y, acc[0][1]);
        acc[0][2] = fmaf(a0, w.z, acc[0][2]);
        acc[0][3] = fmaf(a0, w.w, acc[0][3]);
        acc[1][0] = fmaf(a1, w.x, acc[1][0]);
        acc[1][1] = fmaf(a1, w.y, acc[1][1]);
        acc[1][2] = fmaf(a1, w.z, acc[1][2]);
        acc[1][3] = fmaf(a1, w.w, acc[1][3]);
        acc[2][0] = fmaf(a2, w.x, acc[2][0]);
        acc[2][1] = fmaf(a2, w.y, acc[2][1]);
        acc[2][2] = fmaf(a2, w.z, acc[2][2]);
        acc[2][3] = fmaf(a2, w.w, acc[2][3]);
        acc[3][0] = fmaf(a3, w.x, acc[3][0]);
        acc[3][1] = fmaf(a3, w.y, acc[3][1]);
        acc[3][2] = fmaf(a3, w.z, acc[3][2]);
        acc[3][3] = fmaf(a3, w.w, acc[3][3]);
    }

#pragma unroll
    for (int i = 0; i < 4; ++i) {
        int gr = row0 + r0 + i;
        if (gr < N) {
            float4 o;
            o.x = RELU ? fmaxf(acc[i][0], 0.f) : acc[i][0];
            o.y = RELU ? fmaxf(acc[i][1], 0.f) : acc[i][1];
            o.z = RELU ? fmaxf(acc[i][2], 0.f) : acc[i][2];
            o.w = RELU ? fmaxf(acc[i][3], 0.f) : acc[i][3];
            *(float4*)(out + (size_t)gr * 64 + c0) = o;
        }
    }
}

extern "C" void kernel_launch(void* const* d_in, const int* in_sizes, int n_in,
                              void* d_out, int out_size, void* d_ws, size_t ws_size,
                              hipStream_t stream) {
    const float* x  = (const float*)d_in[0];
    const int* src  = (const int*)d_in[1];
    const int* dst  = (const int*)d_in[2];
    const float* W1 = (const float*)d_in[3];
    const float* b1 = (const float*)d_in[4];
    const float* W2 = (const float*)d_in[5];
    const float* b2 = (const float*)d_in[6];
    const float* W3 = (const float*)d_in[7];
    const float* b3 = (const float*)d_in[8];

    const int N = in_sizes[0] / 64;
    const int E = in_sizes[1];

    float* ybuf = (float*)d_out;                 // reuse output as scaled-feature scratch
    float* bufA = (float*)d_ws;                  // N*64 aggregate
    float* bufH = bufA + (size_t)N * 64;         // N*64 hidden
    int* c_out  = (int*)(bufH + (size_t)N * 64); // N
    int* c_in   = c_out + N;                     // N
    float* r_out = (float*)(c_in + N);           // N
    float* r_in  = r_out + N;                    // N
    float* r_und = r_in + N;                     // N

    const size_t featBytes = (size_t)N * 64 * sizeof(float);
    const int TPB = 256;
    const int gE   = (E + TPB - 1) / TPB;
    const int gN   = (N + TPB - 1) / TPB;
    const int n4   = N * 16;
    const int g4   = (n4 + TPB - 1) / TPB;
    const int gSc  = (int)(((size_t)E * 64 + TPB - 1) / TPB);
    const int gGm  = (N + 63) / 64;

    // degrees
    hipMemsetAsync(c_out, 0, 2 * (size_t)N * sizeof(int), stream);
    deg_count_k<<<gE, TPB, 0, stream>>>(src, dst, c_out, c_in, E);
    deg_finalize_k<<<gN, TPB, 0, stream>>>(c_out, c_in, r_out, r_in, r_und, N);

    // layer 1: 'O' (src -> dst)
    scale_rows_k<<<g4, TPB, 0, stream>>>(x, r_out, ybuf, n4);
    hipMemsetAsync(bufA, 0, featBytes, stream);
    scatter_add_k<<<gSc, TPB, 0, stream>>>(ybuf, src, dst, bufA, E);
    gemm_cat_k<true><<<gGm, TPB, 0, stream>>>(x, bufA, W1, b1, bufH, N);

    // layer 2: 'I' (dst -> src)
    scale_rows_k<<<g4, TPB, 0, stream>>>(bufH, r_in, ybuf, n4);
    hipMemsetAsync(bufA, 0, featBytes, stream);
    scatter_add_k<<<gSc, TPB, 0, stream>>>(ybuf, dst, src, bufA, E);
    gemm_cat_k<true><<<gGm, TPB, 0, stream>>>(bufH, bufA, W2, b2, bufH, N);

    // layer 3: 'U' (both directions)
    scale_rows_k<<<g4, TPB, 0, stream>>>(bufH, r_und, ybuf, n4);
    hipMemsetAsync(bufA, 0, featBytes, stream);
    scatter_add_k<<<gSc, TPB, 0, stream>>>(ybuf, src, dst, bufA, E);
    scatter_add_k<<<gSc, TPB, 0, stream>>>(ybuf, dst, src, bufA, E);
    gemm_cat_k<false><<<gGm, TPB, 0, stream>>>(bufH, bufA, W3, b3, (float*)d_out, N);
}

// Round 2
// 810.860 us; speedup vs baseline: 4.7612x; 4.7612x over previous
//
#include <hip/hip_runtime.h>

// ---------------------------------------------------------------------------
// 3-layer GraphSAGE (DGL GraphConv norm='left'), N=100k, E=1M, D=H=O=64, fp32.
// Round 2: atomic scatter replaced by CSR gather-reduce (wave-per-node).
//   CSR build: histogram -> 3-pass exclusive scan -> cursor fill.
//   agg[n] = sum_{nb in list(n)} h[nb] * r[nb]   (degree recip folded in)
// d_out doubles as the aggregate buffer each layer (block-row ownership makes
// in-place layer-3 GEMM safe). No feature atomics anywhere.
// ---------------------------------------------------------------------------

__global__ void hist_k(const int* __restrict__ src, const int* __restrict__ dst,
                       int* __restrict__ cnt_out, int* __restrict__ cnt_in, int E) {
    int t = blockIdx.x * blockDim.x + threadIdx.x;
    if (t < E) {
        atomicAdd(&cnt_out[src[t]], 1);
        atomicAdd(&cnt_in[dst[t]], 1);
    }
}

__global__ void finalize_r_k(const int* __restrict__ cnt_out, const int* __restrict__ cnt_in,
                             float* __restrict__ r_out, float* __restrict__ r_in,
                             float* __restrict__ r_und, int N) {
    int t = blockIdx.x * blockDim.x + threadIdx.x;
    if (t < N) {
        int a = cnt_out[t], b = cnt_in[t];
        r_out[t] = 1.0f / (float)(a < 1 ? 1 : a);
        r_in[t]  = 1.0f / (float)(b < 1 ? 1 : b);
        int c = a + b;
        r_und[t] = 1.0f / (float)(c < 1 ? 1 : c);
    }
}

// --- exclusive scan over two N-length int arrays (blockIdx.y picks array) ---
__global__ void scan_pass1(const int* __restrict__ c0, const int* __restrict__ c1,
                           int* __restrict__ b0, int* __restrict__ b1, int N) {
    const int* cnt = blockIdx.y ? c1 : c0;
    int* bsum = blockIdx.y ? b1 : b0;
    __shared__ int s[256];
    int base = blockIdx.x * 1024;
    int t = threadIdx.x;
    int v = 0;
    for (int i = t; i < 1024; i += 256) {
        int g = base + i;
        v += (g < N) ? cnt[g] : 0;
    }
    s[t] = v; __syncthreads();
    for (int off = 128; off > 0; off >>= 1) {
        if (t < off) s[t] += s[t + off];
        __syncthreads();
    }
    if (t == 0) bsum[blockIdx.x] = s[0];
}

__global__ void scan_pass2(int* __restrict__ b0, int* __restrict__ b1, int G) {
    int* b = blockIdx.y ? b1 : b0;
    if (threadIdx.x == 0) {
        int acc = 0;
        for (int i = 0; i < G; ++i) { int v = b[i]; b[i] = acc; acc += v; }
    }
}

__global__ void scan_pass3(const int* __restrict__ c0, const int* __restrict__ c1,
                           const int* __restrict__ b0, const int* __restrict__ b1,
                           int* __restrict__ ip0, int* __restrict__ ip1, int N) {
    const int* cnt = blockIdx.y ? c1 : c0;
    const int* bsum = blockIdx.y ? b1 : b0;
    int* ip = blockIdx.y ? ip1 : ip0;
    __shared__ int s[256];
    int t = threadIdx.x;
    int base = blockIdx.x * 1024 + t * 4;
    int v[4]; int tot = 0;
#pragma unroll
    for (int j = 0; j < 4; ++j) {
        int g = base + j;
        v[j] = (g < N) ? cnt[g] : 0;
        tot += v[j];
    }
    s[t] = tot; __syncthreads();
    for (int off = 1; off < 256; off <<= 1) {
        int x = (t >= off) ? s[t - off] : 0;
        __syncthreads();
        s[t] += x;
        __syncthreads();
    }
    int excl = bsum[blockIdx.x] + s[t] - tot;
#pragma unroll
    for (int j = 0; j < 4; ++j) {
        int g = base + j;
        if (g < N) ip[g] = excl;
        excl += v[j];
        if (g == N - 1) ip[N] = excl;   // total == E
    }
}

__global__ void cursor_init_k(const int* __restrict__ ip0, const int* __restrict__ ip1,
                              int* __restrict__ cur0, int* __restrict__ cur1, int N) {
    int t = blockIdx.x * blockDim.x + threadIdx.x;
    if (t < N) { cur0[t] = ip0[t]; cur1[t] = ip1[t]; }
}

__global__ void fill_k(const int* __restrict__ src, const int* __restrict__ dst,
                       int* __restrict__ cur_out, int* __restrict__ cur_in,
                       int* __restrict__ col_out, int* __restrict__ col_in, int E) {
    int e = blockIdx.x * blockDim.x + threadIdx.x;
    if (e < E) {
        int s = src[e], d = dst[e];
        int p = atomicAdd(&cur_in[d], 1);  col_in[p] = s;   // in-CSR: by dst, lists src
        int q = atomicAdd(&cur_out[s], 1); col_out[q] = d;  // out-CSR: by src, lists dst
    }
}

// one wave per node; lane = feature. agg[n][f] = sum h[nb][f] * r[nb]
__global__ void agg_k(const float* __restrict__ h, const int* __restrict__ ip,
                      const int* __restrict__ col, const float* __restrict__ r,
                      float* __restrict__ agg, int N) {
    int node = (blockIdx.x * blockDim.x + threadIdx.x) >> 6;
    int lane = threadIdx.x & 63;
    if (node >= N) return;
    int b = ip[node], e = ip[node + 1];
    float acc = 0.f;
    for (int i = b; i < e; ++i) {
        int nb = col[i];
        acc = fmaf(h[(size_t)nb * 64 + lane], r[nb], acc);
    }
    agg[(size_t)node * 64 + lane] = acc;
}

__global__ void agg_dual_k(const float* __restrict__ h,
                           const int* __restrict__ ipA, const int* __restrict__ colA,
                           const int* __restrict__ ipB, const int* __restrict__ colB,
                           const float* __restrict__ r,
                           float* __restrict__ agg, int N) {
    int node = (blockIdx.x * blockDim.x + threadIdx.x) >> 6;
    int lane = threadIdx.x & 63;
    if (node >= N) return;
    float acc = 0.f;
    int b = ipA[node], e = ipA[node + 1];
    for (int i = b; i < e; ++i) {
        int nb = colA[i];
        acc = fmaf(h[(size_t)nb * 64 + lane], r[nb], acc);
    }
    b = ipB[node]; e = ipB[node + 1];
    for (int i = b; i < e; ++i) {
        int nb = colB[i];
        acc = fmaf(h[(size_t)nb * 64 + lane], r[nb], acc);
    }
    agg[(size_t)node * 64 + lane] = acc;
}

// out = [X, A] @ W + B (optional relu). W: [128][64] row-major.
// 256 threads -> 64x64 tile, 4x4 per-thread. LDS 64KB. X/A tiles XOR-swizzled.
// NOTE: X/out (and A/out) may alias with per-block row ownership -> no restrict.
template <bool RELU>
__global__ __launch_bounds__(256, 2) void gemm_cat_k(
    const float* X, const float* A,
    const float* __restrict__ W, const float* __restrict__ B,
    float* out, int N) {
    __shared__ float sW[128 * 64];
    __shared__ float sX[64 * 64];
    __shared__ float sA[64 * 64];
    const int tid = threadIdx.x;

    for (int i = tid; i < 128 * 64; i += 256) sW[i] = W[i];

    const int row0 = blockIdx.x * 64;
    for (int i = tid; i < 64 * 64; i += 256) {
        int r = i >> 6, c = i & 63;
        int gr = row0 + r;
        int sc = c ^ ((r & 12) << 1);
        float xv = 0.f, av = 0.f;
        if (gr < N) {
            xv = X[(size_t)gr * 64 + c];
            av = A[(size_t)gr * 64 + c];
        }
        sX[(r << 6) + sc] = xv;
        sA[(r << 6) + sc] = av;
    }
    __syncthreads();

    const int c0 = (tid & 15) << 2;
    const int r0 = (tid >> 4) << 2;
    const int sw = (r0 & 12) << 1;

    float4 bv = *(const float4*)(B + c0);
    float acc[4][4];
#pragma unroll
    for (int i = 0; i < 4; ++i) {
        acc[i][0] = bv.x; acc[i][1] = bv.y; acc[i][2] = bv.z; acc[i][3] = bv.w;
    }

#pragma unroll 8
    for (int k = 0; k < 64; ++k) {
        const int kx = k ^ sw;
        float4 w = *(const float4*)&sW[(k << 6) + c0];
        float a0 = sX[((r0 + 0) << 6) + kx];
        float a1 = sX[((r0 + 1) << 6) + kx];
        float a2 = sX[((r0 + 2) << 6) + kx];
        float a3 = sX[((r0 + 3) << 6) + kx];
        acc[0][0] = fmaf(a0, w.x, acc[0][0]); acc[0][1] = fmaf(a0, w.y, acc[0][1]);
        acc[0][2] = fmaf(a0, w.z, acc[0][2]); acc[0][3] = fmaf(a0, w.w, acc[0][3]);
        acc[1][0] = fmaf(a1, w.x, acc[1][0]); acc[1][1] = fmaf(a1, w.y, acc[1][1]);
        acc[1][2] = fmaf(a1, w.z, acc[1][2]); acc[1][3] = fmaf(a1, w.w, acc[1][3]);
        acc[2][0] = fmaf(a2, w.x, acc[2][0]); acc[2][1] = fmaf(a2, w.y, acc[2][1]);
        acc[2][2] = fmaf(a2, w.z, acc[2][2]); acc[2][3] = fmaf(a2, w.w, acc[2][3]);
        acc[3][0] = fmaf(a3, w.x, acc[3][0]); acc[3][1] = fmaf(a3, w.y, acc[3][1]);
        acc[3][2] = fmaf(a3, w.z, acc[3][2]); acc[3][3] = fmaf(a3, w.w, acc[3][3]);
    }
#pragma unroll 8
    for (int k = 0; k < 64; ++k) {
        const int kx = k ^ sw;
        float4 w = *(const float4*)&sW[((k + 64) << 6) + c0];
        float a0 = sA[((r0 + 0) << 6) + kx];
        float a1 = sA[((r0 + 1) << 6) + kx];
        float a2 = sA[((r0 + 2) << 6) + kx];
        float a3 = sA[((r0 + 3) << 6) + kx];
        acc[0][0] = fmaf(a0, w.x, acc[0][0]); acc[0][1] = fmaf(a0, w.y, acc[0][1]);
        acc[0][2] = fmaf(a0, w.z, acc[0][2]); acc[0][3] = fmaf(a0, w.w, acc[0][3]);
        acc[1][0] = fmaf(a1, w.x, acc[1][0]); acc[1][1] = fmaf(a1, w.y, acc[1][1]);
        acc[1][2] = fmaf(a1, w.z, acc[1][2]); acc[1][3] = fmaf(a1, w.w, acc[1][3]);
        acc[2][0] = fmaf(a2, w.x, acc[2][0]); acc[2][1] = fmaf(a2, w.y, acc[2][1]);
        acc[2][2] = fmaf(a2, w.z, acc[2][2]); acc[2][3] = fmaf(a2, w.w, acc[2][3]);
        acc[3][0] = fmaf(a3, w.x, acc[3][0]); acc[3][1] = fmaf(a3, w.y, acc[3][1]);
        acc[3][2] = fmaf(a3, w.z, acc[3][2]); acc[3][3] = fmaf(a3, w.w, acc[3][3]);
    }

#pragma unroll
    for (int i = 0; i < 4; ++i) {
        int gr = row0 + r0 + i;
        if (gr < N) {
            float4 o;
            o.x = RELU ? fmaxf(acc[i][0], 0.f) : acc[i][0];
            o.y = RELU ? fmaxf(acc[i][1], 0.f) : acc[i][1];
            o.z = RELU ? fmaxf(acc[i][2], 0.f) : acc[i][2];
            o.w = RELU ? fmaxf(acc[i][3], 0.f) : acc[i][3];
            *(float4*)(out + (size_t)gr * 64 + c0) = o;
        }
    }
}

extern "C" void kernel_launch(void* const* d_in, const int* in_sizes, int n_in,
                              void* d_out, int out_size, void* d_ws, size_t ws_size,
                              hipStream_t stream) {
    const float* x  = (const float*)d_in[0];
    const int* src  = (const int*)d_in[1];
    const int* dst  = (const int*)d_in[2];
    const float* W1 = (const float*)d_in[3];
    const float* b1 = (const float*)d_in[4];
    const float* W2 = (const float*)d_in[5];
    const float* b2 = (const float*)d_in[6];
    const float* W3 = (const float*)d_in[7];
    const float* b3 = (const float*)d_in[8];

    const int N = in_sizes[0] / 64;
    const int E = in_sizes[1];

    // workspace layout
    float* bufH  = (float*)d_ws;                      // N*64 hidden
    int* cnt_out = (int*)(bufH + (size_t)N * 64);     // N
    int* cnt_in  = cnt_out + N;                       // N
    int* ip_out  = cnt_in + N;                        // N+1
    int* ip_in   = ip_out + (N + 1);                  // N+1
    int* cur_out = ip_in + (N + 1);                   // N
    int* cur_in  = cur_out + N;                       // N
    int* bs_out  = cur_in + N;                        // 1024
    int* bs_in   = bs_out + 1024;                     // 1024
    float* r_out = (float*)(bs_in + 1024);            // N
    float* r_in  = r_out + N;                         // N
    float* r_und = r_in + N;                          // N
    int* col_out = (int*)(r_und + N);                 // E
    int* col_in  = col_out + E;                       // E

    float* aggB = (float*)d_out;   // aggregate buffer doubles as output

    const int TPB = 256;
    const int gE  = (E + TPB - 1) / TPB;
    const int gN  = (N + TPB - 1) / TPB;
    const int gAg = (int)(((size_t)N * 64 + TPB - 1) / TPB);
    const int gGm = (N + 63) / 64;
    const int G   = (N + 1023) / 1024;

    // --- CSR build ---
    hipMemsetAsync(cnt_out, 0, 2 * (size_t)N * sizeof(int), stream);
    hist_k<<<gE, TPB, 0, stream>>>(src, dst, cnt_out, cnt_in, E);
    finalize_r_k<<<gN, TPB, 0, stream>>>(cnt_out, cnt_in, r_out, r_in, r_und, N);
    scan_pass1<<<dim3(G, 2), TPB, 0, stream>>>(cnt_out, cnt_in, bs_out, bs_in, N);
    scan_pass2<<<dim3(1, 2), 64, 0, stream>>>(bs_out, bs_in, G);
    scan_pass3<<<dim3(G, 2), TPB, 0, stream>>>(cnt_out, cnt_in, bs_out, bs_in, ip_out, ip_in, N);
    cursor_init_k<<<gN, TPB, 0, stream>>>(ip_out, ip_in, cur_out, cur_in, N);
    fill_k<<<gE, TPB, 0, stream>>>(src, dst, cur_out, cur_in, col_out, col_in, E);

    // --- layer 1: 'O' — for node n, sum over in-edges: x[src]/outdeg[src] ---
    agg_k<<<gAg, TPB, 0, stream>>>(x, ip_in, col_in, r_out, aggB, N);
    gemm_cat_k<true><<<gGm, TPB, 0, stream>>>(x, aggB, W1, b1, bufH, N);

    // --- layer 2: 'I' — for node n, sum over out-edges: h[dst]/indeg[dst] ---
    agg_k<<<gAg, TPB, 0, stream>>>(bufH, ip_out, col_out, r_in, aggB, N);
    gemm_cat_k<true><<<gGm, TPB, 0, stream>>>(bufH, aggB, W2, b2, bufH, N);

    // --- layer 3: 'U' — both directions, scale by undirected degree ---
    agg_dual_k<<<gAg, TPB, 0, stream>>>(bufH, ip_in, col_in, ip_out, col_out, r_und, aggB, N);
    gemm_cat_k<false><<<gGm, TPB, 0, stream>>>(bufH, aggB, W3, b3, (float*)d_out, N);
}

// Round 3
// 570.173 us; speedup vs baseline: 6.7710x; 1.4221x over previous
//
#include <hip/hip_runtime.h>

// ---------------------------------------------------------------------------
// 3-layer GraphSAGE (DGL GraphConv norm='left'), N=100k, E=1M, D=H=O=64, fp32.
// Round 3: ILP-restructured gather (coalesced col + shuffle broadcast, 4 row
// loads in flight), degree-reciprocal pre-folded into gathered features
// (standalone scale for layer 1, fused into GEMM epilogue for layers 2/3).
// ---------------------------------------------------------------------------

__global__ void hist_k(const int* __restrict__ src, const int* __restrict__ dst,
                       int* __restrict__ cnt_out, int* __restrict__ cnt_in, int E) {
    int t = blockIdx.x * blockDim.x + threadIdx.x;
    if (t < E) {
        atomicAdd(&cnt_out[src[t]], 1);
        atomicAdd(&cnt_in[dst[t]], 1);
    }
}

__global__ void finalize_r_k(const int* __restrict__ cnt_out, const int* __restrict__ cnt_in,
                             float* __restrict__ r_out, float* __restrict__ r_in,
                             float* __restrict__ r_und, int N) {
    int t = blockIdx.x * blockDim.x + threadIdx.x;
    if (t < N) {
        int a = cnt_out[t], b = cnt_in[t];
        r_out[t] = 1.0f / (float)(a < 1 ? 1 : a);
        r_in[t]  = 1.0f / (float)(b < 1 ? 1 : b);
        int c = a + b;
        r_und[t] = 1.0f / (float)(c < 1 ? 1 : c);
    }
}

// --- exclusive scan over two N-length int arrays (blockIdx.y picks array) ---
__global__ void scan_pass1(const int* __restrict__ c0, const int* __restrict__ c1,
                           int* __restrict__ b0, int* __restrict__ b1, int N) {
    const int* cnt = blockIdx.y ? c1 : c0;
    int* bsum = blockIdx.y ? b1 : b0;
    __shared__ int s[256];
    int base = blockIdx.x * 1024;
    int t = threadIdx.x;
    int v = 0;
    for (int i = t; i < 1024; i += 256) {
        int g = base + i;
        v += (g < N) ? cnt[g] : 0;
    }
    s[t] = v; __syncthreads();
    for (int off = 128; off > 0; off >>= 1) {
        if (t < off) s[t] += s[t + off];
        __syncthreads();
    }
    if (t == 0) bsum[blockIdx.x] = s[0];
}

__global__ void scan_pass2(int* __restrict__ b0, int* __restrict__ b1, int G) {
    int* b = blockIdx.y ? b1 : b0;
    if (threadIdx.x == 0) {
        int acc = 0;
        for (int i = 0; i < G; ++i) { int v = b[i]; b[i] = acc; acc += v; }
    }
}

// also writes the atomic cursors (cur = ip) so fill_k can run immediately
__global__ void scan_pass3(const int* __restrict__ c0, const int* __restrict__ c1,
                           const int* __restrict__ b0, const int* __restrict__ b1,
                           int* __restrict__ ip0, int* __restrict__ ip1,
                           int* __restrict__ cur0, int* __restrict__ cur1, int N) {
    const int* cnt = blockIdx.y ? c1 : c0;
    const int* bsum = blockIdx.y ? b1 : b0;
    int* ip  = blockIdx.y ? ip1 : ip0;
    int* cur = blockIdx.y ? cur1 : cur0;
    __shared__ int s[256];
    int t = threadIdx.x;
    int base = blockIdx.x * 1024 + t * 4;
    int v[4]; int tot = 0;
#pragma unroll
    for (int j = 0; j < 4; ++j) {
        int g = base + j;
        v[j] = (g < N) ? cnt[g] : 0;
        tot += v[j];
    }
    s[t] = tot; __syncthreads();
    for (int off = 1; off < 256; off <<= 1) {
        int x = (t >= off) ? s[t - off] : 0;
        __syncthreads();
        s[t] += x;
        __syncthreads();
    }
    int excl = bsum[blockIdx.x] + s[t] - tot;
#pragma unroll
    for (int j = 0; j < 4; ++j) {
        int g = base + j;
        if (g < N) { ip[g] = excl; cur[g] = excl; }
        excl += v[j];
        if (g == N - 1) ip[N] = excl;   // total == E
    }
}

__global__ void fill_k(const int* __restrict__ src, const int* __restrict__ dst,
                       int* __restrict__ cur_out, int* __restrict__ cur_in,
                       int* __restrict__ col_out, int* __restrict__ col_in, int E) {
    int e = blockIdx.x * blockDim.x + threadIdx.x;
    if (e < E) {
        int s = src[e], d = dst[e];
        int p = atomicAdd(&cur_in[d], 1);  col_in[p] = s;   // in-CSR: by dst, lists src
        int q = atomicAdd(&cur_out[s], 1); col_out[q] = d;  // out-CSR: by src, lists dst
    }
}

// hs[row] = in[row] * r[row] (float4)
__global__ void scale_rows_k(const float* __restrict__ in, const float* __restrict__ r,
                             float* __restrict__ out, int n4) {
    int t = blockIdx.x * blockDim.x + threadIdx.x;
    if (t < n4) {
        float s = r[t >> 4];
        float4 v = ((const float4*)in)[t];
        v.x *= s; v.y *= s; v.z *= s; v.w *= s;
        ((float4*)out)[t] = v;
    }
}

// one wave per node; lane = feature. agg[n][f] = sum_{nb} hs[nb][f]
// col ids loaded 64-at-a-time coalesced, broadcast via shuffle; 4 independent
// row-gathers in flight per unroll group.
__global__ void agg_k(const float* __restrict__ hs, const int* __restrict__ ip,
                      const int* __restrict__ col, float* __restrict__ agg, int N) {
    int node = (blockIdx.x * blockDim.x + threadIdx.x) >> 6;
    int lane = threadIdx.x & 63;
    if (node >= N) return;
    int b = ip[node], e = ip[node + 1];
    float acc = 0.f;
    for (int base = b; base < e; base += 64) {
        int cnt = e - base; if (cnt > 64) cnt = 64;
        int my = (lane < cnt) ? col[base + lane] : 0;
        int j = 0;
        for (; j + 4 <= cnt; j += 4) {
            int n0 = __shfl(my, j + 0);
            int n1 = __shfl(my, j + 1);
            int n2 = __shfl(my, j + 2);
            int n3 = __shfl(my, j + 3);
            float v0 = hs[(size_t)n0 * 64 + lane];
            float v1 = hs[(size_t)n1 * 64 + lane];
            float v2 = hs[(size_t)n2 * 64 + lane];
            float v3 = hs[(size_t)n3 * 64 + lane];
            acc += v0; acc += v1; acc += v2; acc += v3;
        }
        for (; j < cnt; ++j) {
            int nb = __shfl(my, j);
            acc += hs[(size_t)nb * 64 + lane];
        }
    }
    agg[(size_t)node * 64 + lane] = acc;
}

__global__ void agg_dual_k(const float* __restrict__ hs,
                           const int* __restrict__ ipA, const int* __restrict__ colA,
                           const int* __restrict__ ipB, const int* __restrict__ colB,
                           float* __restrict__ agg, int N) {
    int node = (blockIdx.x * blockDim.x + threadIdx.x) >> 6;
    int lane = threadIdx.x & 63;
    if (node >= N) return;
    float acc = 0.f;
#pragma unroll 1
    for (int pass = 0; pass < 2; ++pass) {
        const int* ip  = pass ? ipB : ipA;
        const int* col = pass ? colB : colA;
        int b = ip[node], e = ip[node + 1];
        for (int base = b; base < e; base += 64) {
            int cnt = e - base; if (cnt > 64) cnt = 64;
            int my = (lane < cnt) ? col[base + lane] : 0;
            int j = 0;
            for (; j + 4 <= cnt; j += 4) {
                int n0 = __shfl(my, j + 0);
                int n1 = __shfl(my, j + 1);
                int n2 = __shfl(my, j + 2);
                int n3 = __shfl(my, j + 3);
                float v0 = hs[(size_t)n0 * 64 + lane];
                float v1 = hs[(size_t)n1 * 64 + lane];
                float v2 = hs[(size_t)n2 * 64 + lane];
                float v3 = hs[(size_t)n3 * 64 + lane];
                acc += v0; acc += v1; acc += v2; acc += v3;
            }
            for (; j < cnt; ++j) {
                int nb = __shfl(my, j);
                acc += hs[(size_t)nb * 64 + lane];
            }
        }
    }
    agg[(size_t)node * 64 + lane] = acc;
}

// out = [X, A] @ W + B (optional relu); optionally also hs_out = out * rs[row]
// (pre-scaled features for the NEXT layer's gather, fused in the epilogue).
// 256 threads -> 64x64 tile, 4x4 per-thread. LDS 64KB. X/A tiles XOR-swizzled
// (col ^ ((row&12)<<1)): within a wave the 4 row-groups land in 4 distinct
// banks (verified: SQ_LDS_BANK_CONFLICT == 0). Staging is float4-vectorized;
// the swizzle is 8-aligned so float4 stores stay contiguous.
// X/out and A/out may alias (per-block row ownership) -> no restrict.
template <bool RELU, bool WRITE_HS>
__global__ __launch_bounds__(256, 2) void gemm_cat_k(
    const float* X, const float* A,
    const float* __restrict__ W, const float* __restrict__ B,
    const float* __restrict__ rs, float* __restrict__ hs_out,
    float* out, int N) {
    __shared__ float sW[128 * 64];
    __shared__ float sX[64 * 64];
    __shared__ float sA[64 * 64];
    const int tid = threadIdx.x;

    for (int i = tid; i < 2048; i += 256) ((float4*)sW)[i] = ((const float4*)W)[i];

    const int row0 = blockIdx.x * 64;
    for (int i = tid; i < 1024; i += 256) {
        int r = i >> 4, c4 = (i & 15) << 2;
        int gr = row0 + r;
        float4 xv = make_float4(0.f, 0.f, 0.f, 0.f), av = xv;
        if (gr < N) {
            xv = ((const float4*)X)[(size_t)gr * 16 + (i & 15)];
            av = ((const float4*)A)[(size_t)gr * 16 + (i & 15)];
        }
        int sc = c4 ^ ((r & 12) << 1);
        *(float4*)&sX[(r << 6) + sc] = xv;
        *(float4*)&sA[(r << 6) + sc] = av;
    }
    __syncthreads();

    const int c0 = (tid & 15) << 2;
    const int r0 = (tid >> 4) << 2;
    const int sw = (r0 & 12) << 1;

    float4 bv = *(const float4*)(B + c0);
    float acc[4][4];
#pragma unroll
    for (int i = 0; i < 4; ++i) {
        acc[i][0] = bv.x; acc[i][1] = bv.y; acc[i][2] = bv.z; acc[i][3] = bv.w;
    }

#pragma unroll 8
    for (int k = 0; k < 64; ++k) {
        const int kx = k ^ sw;
        float4 w = *(const float4*)&sW[(k << 6) + c0];
        float a0 = sX[((r0 + 0) << 6) + kx];
        float a1 = sX[((r0 + 1) << 6) + kx];
        float a2 = sX[((r0 + 2) << 6) + kx];
        float a3 = sX[((r0 + 3) << 6) + kx];
        acc[0][0] = fmaf(a0, w.x, acc[0][0]); acc[0][1] = fmaf(a0, w.y, acc[0][1]);
        acc[0][2] = fmaf(a0, w.z, acc[0][2]); acc[0][3] = fmaf(a0, w.w, acc[0][3]);
        acc[1][0] = fmaf(a1, w.x, acc[1][0]); acc[1][1] = fmaf(a1, w.y, acc[1][1]);
        acc[1][2] = fmaf(a1, w.z, acc[1][2]); acc[1][3] = fmaf(a1, w.w, acc[1][3]);
        acc[2][0] = fmaf(a2, w.x, acc[2][0]); acc[2][1] = fmaf(a2, w.y, acc[2][1]);
        acc[2][2] = fmaf(a2, w.z, acc[2][2]); acc[2][3] = fmaf(a2, w.w, acc[2][3]);
        acc[3][0] = fmaf(a3, w.x, acc[3][0]); acc[3][1] = fmaf(a3, w.y, acc[3][1]);
        acc[3][2] = fmaf(a3, w.z, acc[3][2]); acc[3][3] = fmaf(a3, w.w, acc[3][3]);
    }
#pragma unroll 8
    for (int k = 0; k < 64; ++k) {
        const int kx = k ^ sw;
        float4 w = *(const float4*)&sW[((k + 64) << 6) + c0];
        float a0 = sA[((r0 + 0) << 6) + kx];
        float a1 = sA[((r0 + 1) << 6) + kx];
        float a2 = sA[((r0 + 2) << 6) + kx];
        float a3 = sA[((r0 + 3) << 6) + kx];
        acc[0][0] = fmaf(a0, w.x, acc[0][0]); acc[0][1] = fmaf(a0, w.y, acc[0][1]);
        acc[0][2] = fmaf(a0, w.z, acc[0][2]); acc[0][3] = fmaf(a0, w.w, acc[0][3]);
        acc[1][0] = fmaf(a1, w.x, acc[1][0]); acc[1][1] = fmaf(a1, w.y, acc[1][1]);
        acc[1][2] = fmaf(a1, w.z, acc[1][2]); acc[1][3] = fmaf(a1, w.w, acc[1][3]);
        acc[2][0] = fmaf(a2, w.x, acc[2][0]); acc[2][1] = fmaf(a2, w.y, acc[2][1]);
        acc[2][2] = fmaf(a2, w.z, acc[2][2]); acc[2][3] = fmaf(a2, w.w, acc[2][3]);
        acc[3][0] = fmaf(a3, w.x, acc[3][0]); acc[3][1] = fmaf(a3, w.y, acc[3][1]);
        acc[3][2] = fmaf(a3, w.z, acc[3][2]); acc[3][3] = fmaf(a3, w.w, acc[3][3]);
    }

#pragma unroll
    for (int i = 0; i < 4; ++i) {
        int gr = row0 + r0 + i;
        if (gr < N) {
            float4 o;
            o.x = RELU ? fmaxf(acc[i][0], 0.f) : acc[i][0];
            o.y = RELU ? fmaxf(acc[i][1], 0.f) : acc[i][1];
            o.z = RELU ? fmaxf(acc[i][2], 0.f) : acc[i][2];
            o.w = RELU ? fmaxf(acc[i][3], 0.f) : acc[i][3];
            *(float4*)(out + (size_t)gr * 64 + c0) = o;
            if (WRITE_HS) {
                float rr = rs[gr];
                float4 hsv = make_float4(o.x * rr, o.y * rr, o.z * rr, o.w * rr);
                *(float4*)(hs_out + (size_t)gr * 64 + c0) = hsv;
            }
        }
    }
}

extern "C" void kernel_launch(void* const* d_in, const int* in_sizes, int n_in,
                              void* d_out, int out_size, void* d_ws, size_t ws_size,
                              hipStream_t stream) {
    const float* x  = (const float*)d_in[0];
    const int* src  = (const int*)d_in[1];
    const int* dst  = (const int*)d_in[2];
    const float* W1 = (const float*)d_in[3];
    const float* b1 = (const float*)d_in[4];
    const float* W2 = (const float*)d_in[5];
    const float* b2 = (const float*)d_in[6];
    const float* W3 = (const float*)d_in[7];
    const float* b3 = (const float*)d_in[8];

    const int N = in_sizes[0] / 64;
    const int E = in_sizes[1];

    // workspace layout
    float* bufH  = (float*)d_ws;                      // N*64 hidden (h1, h2)
    float* bufHS = bufH + (size_t)N * 64;             // N*64 pre-scaled features
    int* cnt_out = (int*)(bufHS + (size_t)N * 64);    // N
    int* cnt_in  = cnt_out + N;                       // N
    int* ip_out  = cnt_in + N;                        // N+1
    int* ip_in   = ip_out + (N + 1);                  // N+1
    int* cur_out = ip_in + (N + 1);                   // N
    int* cur_in  = cur_out + N;                       // N
    int* bs_out  = cur_in + N;                        // 1024
    int* bs_in   = bs_out + 1024;                     // 1024
    float* r_out = (float*)(bs_in + 1024);            // N
    float* r_in  = r_out + N;                         // N
    float* r_und = r_in + N;                          // N
    int* col_out = (int*)(r_und + N);                 // E
    int* col_in  = col_out + E;                       // E

    float* aggB = (float*)d_out;   // aggregate buffer doubles as output

    const int TPB = 256;
    const int gE  = (E + TPB - 1) / TPB;
    const int gN  = (N + TPB - 1) / TPB;
    const int n4  = N * 16;
    const int g4  = (n4 + TPB - 1) / TPB;
    const int gAg = (int)(((size_t)N * 64 + TPB - 1) / TPB);
    const int gGm = (N + 63) / 64;
    const int G   = (N + 1023) / 1024;

    // --- CSR build ---
    hipMemsetAsync(cnt_out, 0, 2 * (size_t)N * sizeof(int), stream);
    hist_k<<<gE, TPB, 0, stream>>>(src, dst, cnt_out, cnt_in, E);
    finalize_r_k<<<gN, TPB, 0, stream>>>(cnt_out, cnt_in, r_out, r_in, r_und, N);
    scan_pass1<<<dim3(G, 2), TPB, 0, stream>>>(cnt_out, cnt_in, bs_out, bs_in, N);
    scan_pass2<<<dim3(1, 2), 64, 0, stream>>>(bs_out, bs_in, G);
    scan_pass3<<<dim3(G, 2), TPB, 0, stream>>>(cnt_out, cnt_in, bs_out, bs_in,
                                               ip_out, ip_in, cur_out, cur_in, N);
    fill_k<<<gE, TPB, 0, stream>>>(src, dst, cur_out, cur_in, col_out, col_in, E);

    // --- layer 1: 'O' — agg over in-edges of hs0 = x * r_out ---
    scale_rows_k<<<g4, TPB, 0, stream>>>(x, r_out, bufHS, n4);
    agg_k<<<gAg, TPB, 0, stream>>>(bufHS, ip_in, col_in, aggB, N);
    gemm_cat_k<true, true><<<gGm, TPB, 0, stream>>>(x, aggB, W1, b1, r_in, bufHS, bufH, N);

    // --- layer 2: 'I' — agg over out-edges of hs1 = h1 * r_in ---
    agg_k<<<gAg, TPB, 0, stream>>>(bufHS, ip_out, col_out, aggB, N);
    gemm_cat_k<true, true><<<gGm, TPB, 0, stream>>>(bufH, aggB, W2, b2, r_und, bufHS, bufH, N);

    // --- layer 3: 'U' — agg both directions of hs2 = h2 * r_und ---
    agg_dual_k<<<gAg, TPB, 0, stream>>>(bufHS, ip_in, col_in, ip_out, col_out, aggB, N);
    gemm_cat_k<false, false><<<gGm, TPB, 0, stream>>>(bufH, aggB, W3, b3, nullptr, nullptr,
                                                      (float*)d_out, N);
}